// Round 16
// baseline (532.902 us; speedup 1.0000x reference)
//
#include <hip/hip_runtime.h>

#define N_NODES_C 50000
#define N_EDGES_C 500000
#define EDGE_DIM_C 16
#define DIM_C 128
#define N_LAYERS_C 3
#define N_GRAPHS_C 512
#define N_CLASSES_C 10
#define BN_EPS_C 1e-5f

#define SCAN_NB ((N_NODES_C + 1023) / 1024)

typedef short bf16x8 __attribute__((ext_vector_type(8)));
typedef float f32x4  __attribute__((ext_vector_type(4)));

__device__ inline unsigned cvt_pk_bf16(float a, float b) {
    unsigned r;
    asm("v_cvt_pk_bf16_f32 %0, %1, %2" : "=v"(r) : "v"(a), "v"(b));
    return r;
}
__device__ inline float bf2f(unsigned short h) {
    union { unsigned u; float f; } v; v.u = ((unsigned)h) << 16;
    return v.f;
}
// non-temporal 8-byte load of 4 bf16 (emb row slice) — bypass L2 pollution
__device__ inline ushort4 nt_load_e4(const unsigned short* p) {
    const unsigned* q = (const unsigned*)p;
    unsigned a = __builtin_nontemporal_load(q);
    unsigned b = __builtin_nontemporal_load(q + 1);
    ushort4 r;
    r.x = (unsigned short)(a & 0xffff); r.y = (unsigned short)(a >> 16);
    r.z = (unsigned short)(b & 0xffff); r.w = (unsigned short)(b >> 16);
    return r;
}

// -------------------------------------------------------------------------
// Preprocessing: counting sort of edges by dst (once per launch)
// -------------------------------------------------------------------------
__global__ void hist_kernel(const int* __restrict__ dst, int* __restrict__ cnt)
{
    int e = blockIdx.x * blockDim.x + threadIdx.x;
    if (e < N_EDGES_C) atomicAdd(&cnt[dst[e]], 1);
}

__global__ __launch_bounds__(1024)
void scan1_kernel(const int* __restrict__ cnt, int* __restrict__ incl,
                  int* __restrict__ bsum)
{
    __shared__ int buf[1024];
    int i = blockIdx.x * 1024 + threadIdx.x;
    int v = (i < N_NODES_C) ? cnt[i] : 0;
    buf[threadIdx.x] = v;
    __syncthreads();
    for (int off = 1; off < 1024; off <<= 1) {
        int t = (threadIdx.x >= off) ? buf[threadIdx.x - off] : 0;
        __syncthreads();
        buf[threadIdx.x] += t;
        __syncthreads();
    }
    if (i < N_NODES_C) incl[i] = buf[threadIdx.x];
    if (threadIdx.x == 1023) bsum[blockIdx.x] = buf[1023];
}

__global__ void scan2_kernel(int* __restrict__ bsum)
{
    if (threadIdx.x == 0 && blockIdx.x == 0) {
        int run = 0;
        for (int b = 0; b < SCAN_NB; ++b) { int v = bsum[b]; bsum[b] = run; run += v; }
    }
}

__global__ __launch_bounds__(1024)
void scan3_kernel(const int* __restrict__ cnt, const int* __restrict__ incl,
                  const int* __restrict__ bsum,
                  int* __restrict__ offsets, int* __restrict__ cursor)
{
    int i = blockIdx.x * 1024 + threadIdx.x;
    if (i < N_NODES_C) {
        int inc = incl[i] + bsum[blockIdx.x];
        offsets[i + 1] = inc;
        cursor[i] = inc - cnt[i];
        if (i == 0) offsets[0] = 0;
    }
}

// permute edges by dst; edge_attr converted to bf16 (32 B/edge random write)
__global__ void scatter_kernel(const int* __restrict__ src,
                               const int* __restrict__ dst,
                               const float* __restrict__ ea,
                               int* __restrict__ cursor,
                               int* __restrict__ srcPerm,
                               unsigned short* __restrict__ eaPermH)
{
    int e = blockIdx.x * blockDim.x + threadIdx.x;
    if (e >= N_EDGES_C) return;
    int pos = atomicAdd(&cursor[dst[e]], 1);
    srcPerm[pos] = src[e];
    const float4* in = (const float4*)&ea[(size_t)e * EDGE_DIM_C];
    float4 a = in[0], b = in[1], c = in[2], d = in[3];
    uint4 lo, hi;
    lo.x = cvt_pk_bf16(a.x, a.y); lo.y = cvt_pk_bf16(a.z, a.w);
    lo.z = cvt_pk_bf16(b.x, b.y); lo.w = cvt_pk_bf16(b.z, b.w);
    hi.x = cvt_pk_bf16(c.x, c.y); hi.y = cvt_pk_bf16(c.z, c.w);
    hi.z = cvt_pk_bf16(d.x, d.y); hi.w = cvt_pk_bf16(d.z, d.w);
    uint4* outp = (uint4*)&eaPermH[(size_t)pos * EDGE_DIM_C];
    outp[0] = lo; outp[1] = hi;
}

// convert input node features f32 -> bf16 (once per launch)
__global__ __launch_bounds__(256)
void xcvt_kernel(const float* __restrict__ x, unsigned short* __restrict__ xh)
{
    const int total = N_NODES_C * DIM_C / 4;
    for (int i = blockIdx.x * blockDim.x + threadIdx.x; i < total;
         i += gridDim.x * blockDim.x) {
        float4 v = *(const float4*)&x[(size_t)i * 4];
        uint2 o;
        o.x = cvt_pk_bf16(v.x, v.y);
        o.y = cvt_pk_bf16(v.z, v.w);
        *(uint2*)&xh[(size_t)i * 4] = o;
    }
}

// graph boundaries: goff[g] = lower_bound(batch, g); batch is sorted
__global__ __launch_bounds__(512)
void goff_kernel(const int* __restrict__ batch, int* __restrict__ goff)
{
    int g = threadIdx.x;
    int lo = 0, hi = N_NODES_C;
    while (lo < hi) {
        int mid = (lo + hi) >> 1;
        if (batch[mid] < g) lo = mid + 1; else hi = mid;
    }
    goff[g] = lo;
    if (g == 0) goff[N_GRAPHS_C] = N_NODES_C;
}

// -------------------------------------------------------------------------
// Weight prep: transpose + bf16-convert all GEMM weights once per launch.
// -------------------------------------------------------------------------
__global__ __launch_bounds__(256)
void wprep_kernel(const float* __restrict__ ee_w1, const float* __restrict__ ee_w2,
                  const float* __restrict__ mlp_w1, const float* __restrict__ mlp_w2,
                  short* __restrict__ W1T, short* __restrict__ W2T,
                  short* __restrict__ MT1, short* __restrict__ MT2)
{
    int b = blockIdx.x;
    int l = b % 3;
    int which = b / 3;
    if (which == 0) {
        const float* in = ee_w1 + l * 16 * 128;
        short* outp = W1T + l * 128 * 16;
        for (int i = threadIdx.x; i < 2048; i += 256) {
            int f = i >> 4, k = i & 15;
            outp[i] = (short)(cvt_pk_bf16(in[k * 128 + f], 0.f) & 0xffff);
        }
    } else {
        const float* in = (which == 1 ? ee_w2 : which == 2 ? mlp_w1 : mlp_w2) + l * 128 * 128;
        short* outp = (which == 1 ? W2T : which == 2 ? MT1 : MT2) + l * 128 * 128;
        for (int i = threadIdx.x; i < 16384; i += 256) {
            int f = i >> 7, k = i & 127;
            outp[i] = (short)(cvt_pk_bf16(in[k * 128 + f], 0.f) & 0xffff);
        }
    }
}

// -------------------------------------------------------------------------
// MFMA edge-encoder: 64-edge tile, 4 waves x 32 cols (VGPR ~92).
// emb output staged in LDS then stored coalesced NON-TEMPORAL (write-once
// stream; keep L2 for xh/weights). grid=1024 (measured opt).
// -------------------------------------------------------------------------
__global__ __launch_bounds__(256)
void emb_mfma(const unsigned short* __restrict__ eaPermH,
              const short* __restrict__ W1T, const float* __restrict__ b1,
              const short* __restrict__ W2T, const float* __restrict__ b2,
              const float* __restrict__ bng, const float* __restrict__ bnb,
              const float* __restrict__ bnrm, const float* __restrict__ bnrv,
              unsigned short* __restrict__ emb, int c0, int chunkN)
{
    __shared__ short t1s[64 * 128];   // 16 KB; t1, then e

    const int tid  = threadIdx.x;
    const int lane = tid & 63;
    const int w    = tid >> 6;       // col-group 0..3
    const int ln15 = lane & 15;
    const int g    = lane >> 4;
    const int colbase = w * 32;

    bf16x8 fw1[2], fw2[2][4];
    float b1v[2], b2v[2], scv[2], shv[2];
    #pragma unroll
    for (int ct = 0; ct < 2; ++ct) {
        int f = colbase + ct * 16 + ln15;
        if (g < 2) fw1[ct] = *(const bf16x8*)&W1T[f * 16 + g * 8];
        else       fw1[ct] = (bf16x8){0,0,0,0,0,0,0,0};
        #pragma unroll
        for (int kb = 0; kb < 4; ++kb)
            fw2[ct][kb] = *(const bf16x8*)&W2T[f * 128 + kb * 32 + g * 8];
        b1v[ct] = b1[f]; b2v[ct] = b2[f];
        float sc = bng[f] * rsqrtf(bnrv[f] + BN_EPS_C);
        scv[ct] = sc; shv[ct] = bnb[f] - bnrm[f] * sc;
    }

    const int niter = (chunkN + 63) / 64;
    for (int it = blockIdx.x; it < niter; it += gridDim.x) {
        const int eb = it * 64;

        // ---- stage1: t1 = relu(ea @ W1 + b1), K=16 zero-padded to 32 ----
        #pragma unroll
        for (int rt = 0; rt < 4; ++rt) {
            bf16x8 af;
            if (g < 2) {
                int erow = min(eb + rt * 16 + ln15, chunkN - 1);
                af = *(const bf16x8*)&eaPermH[(size_t)(c0 + erow) * EDGE_DIM_C + g * 8];
            } else {
                af = (bf16x8){0,0,0,0,0,0,0,0};
            }
            #pragma unroll
            for (int ct = 0; ct < 2; ++ct) {
                f32x4 a1 = { b1v[ct], b1v[ct], b1v[ct], b1v[ct] };
                a1 = __builtin_amdgcn_mfma_f32_16x16x32_bf16(af, fw1[ct], a1, 0, 0, 0);
                int col = colbase + ct * 16 + ln15;
                #pragma unroll
                for (int r = 0; r < 4; ++r) {
                    int row = rt * 16 + g * 4 + r;
                    int idx = (row * 128 + col) ^ ((row & 15) << 3);
                    t1s[idx] = (short)(cvt_pk_bf16(fmaxf(a1[r], 0.f), 0.f) & 0xffff);
                }
            }
        }
        __syncthreads();

        // ---- stage2: acc = t1 @ W2 + b2 ----
        f32x4 acc[4][2];
        #pragma unroll
        for (int rt = 0; rt < 4; ++rt)
            #pragma unroll
            for (int ct = 0; ct < 2; ++ct)
                acc[rt][ct] = (f32x4){ b2v[ct], b2v[ct], b2v[ct], b2v[ct] };

        #pragma unroll
        for (int rt = 0; rt < 4; ++rt) {
            bf16x8 a[4];
            int row = rt * 16 + ln15;
            #pragma unroll
            for (int kb = 0; kb < 4; ++kb) {
                int idx = (row * 128 + kb * 32 + g * 8) ^ ((row & 15) << 3);
                a[kb] = *(const bf16x8*)&t1s[idx];
            }
            #pragma unroll
            for (int ct = 0; ct < 2; ++ct)
                #pragma unroll
                for (int kb = 0; kb < 4; ++kb)
                    acc[rt][ct] = __builtin_amdgcn_mfma_f32_16x16x32_bf16(
                        a[kb], fw2[ct][kb], acc[rt][ct], 0, 0, 0);
        }
        __syncthreads();   // all reads of t1s done before overwrite

        // ---- epilogue: e = BN(relu(acc)) -> bf16 back into t1s ----
        #pragma unroll
        for (int rt = 0; rt < 4; ++rt)
            #pragma unroll
            for (int ct = 0; ct < 2; ++ct) {
                int col = colbase + ct * 16 + ln15;
                #pragma unroll
                for (int r = 0; r < 4; ++r) {
                    int row = rt * 16 + g * 4 + r;
                    float v = fmaxf(acc[rt][ct][r], 0.f) * scv[ct] + shv[ct];
                    int idx = (row * 128 + col) ^ ((row & 15) << 3);
                    t1s[idx] = (short)(cvt_pk_bf16(v, 0.f) & 0xffff);
                }
            }
        __syncthreads();

        // ---- coalesced NT store: 64 rows x 128 cols bf16 = 1024 short8 ----
        for (int i = tid; i < 1024; i += 256) {
            int row = i >> 4;
            int c8  = (i & 15) * 8;
            if (eb + row < chunkN) {
                int idx = (row * 128 + c8) ^ ((row & 15) << 3);
                bf16x8 v = *(const bf16x8*)&t1s[idx];
                __builtin_nontemporal_store(v,
                    (bf16x8*)&emb[(size_t)(eb + row) * 128 + c8]);
            }
        }
        __syncthreads();
    }
}

// -------------------------------------------------------------------------
// CSR aggregation (atomic-free): 32 lanes per node, 8 nodes per block.
// x gathered as bf16 rows; emb stream non-temporal. f32 agg across chunks.
// -------------------------------------------------------------------------
__global__ __launch_bounds__(256)
void agg_kernel(const unsigned short* __restrict__ emb,
                const unsigned short* __restrict__ xh,
                const int* __restrict__ srcPerm,
                const int* __restrict__ offsets,
                float* __restrict__ agg,
                int c0, int c1, int first)
{
    const int slot = threadIdx.x >> 5;
    const int l    = threadIdx.x & 31;
    const int n = blockIdx.x * 8 + slot;
    if (n >= N_NODES_C) return;

    int lo = offsets[n], hi = offsets[n + 1];
    lo = max(lo, c0); hi = min(hi, c1);

    float4 s = make_float4(0.f, 0.f, 0.f, 0.f);
    const bool any = lo < hi;
    for (int pos = lo; pos < hi; ++pos) {
        int srcn = srcPerm[pos];
        ushort4 eb = nt_load_e4(&emb[(size_t)(pos - c0) * DIM_C + l * 4]);
        ushort4 xv = *(const ushort4*)&xh[(size_t)srcn * DIM_C + l * 4];
        s.x += fmaxf(bf2f(xv.x) + bf2f(eb.x), 0.f);
        s.y += fmaxf(bf2f(xv.y) + bf2f(eb.y), 0.f);
        s.z += fmaxf(bf2f(xv.z) + bf2f(eb.z), 0.f);
        s.w += fmaxf(bf2f(xv.w) + bf2f(eb.w), 0.f);
    }

    float4* ap = (float4*)&agg[(size_t)n * DIM_C + l * 4];
    if (first) {
        *ap = s;
    } else if (any) {
        float4 o = *ap;
        o.x += s.x; o.y += s.y; o.z += s.z; o.w += s.w;
        *ap = o;
    }
}

// -------------------------------------------------------------------------
// Fused node MLP: xh' = bf16(BN(relu(relu((xh+agg)@W1+b1)@W2+b2))).
// Reads bf16 xh + f32 agg; writes bf16 xh_next (coalesced via LDS).
// -------------------------------------------------------------------------
__global__ __launch_bounds__(256)
void node_fused(const unsigned short* __restrict__ xh,
                const float* __restrict__ agg,
                const short* __restrict__ WT1, const float* __restrict__ b1,
                const short* __restrict__ WT2, const float* __restrict__ b2,
                const float* __restrict__ bng, const float* __restrict__ bnb,
                const float* __restrict__ bnrm, const float* __restrict__ bnrv,
                unsigned short* __restrict__ xhOut, int nrows)
{
    __shared__ short smem[2 * 64 * 128];   // 32 KB: hs | t1s; t1s reused as out
    short* hs  = smem;
    short* t1s = smem + 64 * 128;
    short* souts = t1s;                    // bf16 out overlay (t1s dead then)

    const int tid  = threadIdx.x;
    const int lane = tid & 63;
    const int w    = tid >> 6;
    const int ln15 = lane & 15;
    const int g    = lane >> 4;
    const int colbase = w * 32;

    bf16x8 fw1[2][4], fw2[2][4];
    float b1v[2], b2v[2], scv[2], shv[2];
    #pragma unroll
    for (int ct = 0; ct < 2; ++ct) {
        int f = colbase + ct * 16 + ln15;
        #pragma unroll
        for (int kb = 0; kb < 4; ++kb) {
            fw1[ct][kb] = *(const bf16x8*)&WT1[f * 128 + kb * 32 + g * 8];
            fw2[ct][kb] = *(const bf16x8*)&WT2[f * 128 + kb * 32 + g * 8];
        }
        b1v[ct] = b1[f]; b2v[ct] = b2[f];
        float sc = bng[f] * rsqrtf(bnrv[f] + BN_EPS_C);
        scv[ct] = sc; shv[ct] = bnb[f] - bnrm[f] * sc;
    }

    const int ntiles = (nrows + 63) / 64;
    for (int t = blockIdx.x; t < ntiles; t += gridDim.x) {
        const int base = t * 64;

        // ---- stage0: (bf16 xh + f32 agg) -> bf16 swizzled hs ----
        for (int i = tid; i < 2048; i += 256) {
            int row = i >> 5;
            int c4  = (i & 31) * 4;
            int rr  = min(base + row, nrows - 1);
            ushort4 xv = *(const ushort4*)&xh[(size_t)rr * DIM_C + c4];
            float4 a1 = *(const float4*)&agg[(size_t)rr * DIM_C + c4];
            float vx = bf2f(xv.x) + a1.x;
            float vy = bf2f(xv.y) + a1.y;
            float vz = bf2f(xv.z) + a1.z;
            float vw = bf2f(xv.w) + a1.w;
            int idx = (row * 128 + c4) ^ ((row & 15) << 3);
            *(unsigned*)&hs[idx]     = cvt_pk_bf16(vx, vy);
            *(unsigned*)&hs[idx + 2] = cvt_pk_bf16(vz, vw);
        }
        __syncthreads();

        // ---- stage1: h1 = relu(hs @ W1 + b1) -> t1s ----
        #pragma unroll
        for (int rt = 0; rt < 4; ++rt) {
            bf16x8 a[4];
            int row = rt * 16 + ln15;
            #pragma unroll
            for (int kb = 0; kb < 4; ++kb) {
                int idx = (row * 128 + kb * 32 + g * 8) ^ ((row & 15) << 3);
                a[kb] = *(const bf16x8*)&hs[idx];
            }
            #pragma unroll
            for (int ct = 0; ct < 2; ++ct) {
                f32x4 a1 = { b1v[ct], b1v[ct], b1v[ct], b1v[ct] };
                #pragma unroll
                for (int kb = 0; kb < 4; ++kb)
                    a1 = __builtin_amdgcn_mfma_f32_16x16x32_bf16(a[kb], fw1[ct][kb], a1, 0, 0, 0);
                int col = colbase + ct * 16 + ln15;
                #pragma unroll
                for (int r = 0; r < 4; ++r) {
                    int orow = rt * 16 + g * 4 + r;
                    int idx = (orow * 128 + col) ^ ((orow & 15) << 3);
                    t1s[idx] = (short)(cvt_pk_bf16(fmaxf(a1[r], 0.f), 0.f) & 0xffff);
                }
            }
        }
        __syncthreads();

        // ---- stage2: acc = t1s @ W2 + b2 (keep in registers) ----
        f32x4 acc[4][2];
        #pragma unroll
        for (int rt = 0; rt < 4; ++rt)
            #pragma unroll
            for (int ct = 0; ct < 2; ++ct)
                acc[rt][ct] = (f32x4){ b2v[ct], b2v[ct], b2v[ct], b2v[ct] };

        #pragma unroll
        for (int rt = 0; rt < 4; ++rt) {
            bf16x8 a[4];
            int row = rt * 16 + ln15;
            #pragma unroll
            for (int kb = 0; kb < 4; ++kb) {
                int idx = (row * 128 + kb * 32 + g * 8) ^ ((row & 15) << 3);
                a[kb] = *(const bf16x8*)&t1s[idx];
            }
            #pragma unroll
            for (int ct = 0; ct < 2; ++ct)
                #pragma unroll
                for (int kb = 0; kb < 4; ++kb)
                    acc[rt][ct] = __builtin_amdgcn_mfma_f32_16x16x32_bf16(
                        a[kb], fw2[ct][kb], acc[rt][ct], 0, 0, 0);
        }
        __syncthreads();   // t1s now dead -> reuse as bf16 out

        // ---- epilogue: BN -> bf16 into souts (swizzled) ----
        #pragma unroll
        for (int rt = 0; rt < 4; ++rt)
            #pragma unroll
            for (int ct = 0; ct < 2; ++ct) {
                int col = colbase + ct * 16 + ln15;
                #pragma unroll
                for (int r = 0; r < 4; ++r) {
                    int row = rt * 16 + g * 4 + r;
                    float v = fmaxf(acc[rt][ct][r], 0.f) * scv[ct] + shv[ct];
                    int idx = (row * 128 + col) ^ ((row & 15) << 3);
                    souts[idx] = (short)(cvt_pk_bf16(v, 0.f) & 0xffff);
                }
            }
        __syncthreads();

        // ---- coalesced store: 64 rows x 16 short8 ----
        for (int i = tid; i < 1024; i += 256) {
            int row = i >> 4;
            int c8  = (i & 15) * 8;
            int orow = base + row;
            if (orow < nrows) {
                int idx = (row * 128 + c8) ^ ((row & 15) << 3);
                bf16x8 v = *(const bf16x8*)&souts[idx];
                *(bf16x8*)&xhOut[(size_t)orow * DIM_C + c8] = v;
            }
        }
        __syncthreads();
    }
}

// -------------------------------------------------------------------------
// Segmented mean pool (bf16 input): one block per graph, batch is sorted.
// -------------------------------------------------------------------------
__global__ __launch_bounds__(128)
void pool2_kernel(const unsigned short* __restrict__ xh,
                  const int* __restrict__ goff,
                  float* __restrict__ pooled)
{
    const int g = blockIdx.x;
    const int tid = threadIdx.x;
    int lo = goff[g], hi = goff[g + 1];
    float s = 0.f;
    for (int n = lo; n < hi; ++n)
        s += bf2f(xh[(size_t)n * DIM_C + tid]);
    float c = (float)max(hi - lo, 1);
    pooled[g * DIM_C + tid] = s / c;
}

// -------------------------------------------------------------------------
// Readout head
// -------------------------------------------------------------------------
__global__ __launch_bounds__(128)
void head_kernel(const float* __restrict__ pooled,
                 const float* __restrict__ l1w,
                 const float* __restrict__ l1b,
                 const float* __restrict__ l2w,
                 const float* __restrict__ l2b,
                 float* __restrict__ out)
{
    const int g = blockIdx.x;
    const int tid = threadIdx.x;
    __shared__ float ps[DIM_C];
    __shared__ float hsx[DIM_C];
    __shared__ float lg[N_CLASSES_C];
    __shared__ float lse;

    ps[tid] = pooled[g * DIM_C + tid];
    __syncthreads();

    float a = l1b[tid];
    for (int k = 0; k < DIM_C; ++k)
        a += ps[k] * l1w[k * DIM_C + tid];
    hsx[tid] = fmaxf(a, 0.f);
    __syncthreads();

    if (tid < N_CLASSES_C) {
        float s = l2b[tid];
        for (int f = 0; f < DIM_C; ++f)
            s += hsx[f] * l2w[f * N_CLASSES_C + tid];
        lg[tid] = s;
    }
    __syncthreads();

    if (tid == 0) {
        float m = lg[0];
        for (int cc = 1; cc < N_CLASSES_C; ++cc) m = fmaxf(m, lg[cc]);
        float s = 0.f;
        for (int cc = 0; cc < N_CLASSES_C; ++cc) s += expf(lg[cc] - m);
        lse = m + logf(s);
    }
    __syncthreads();

    if (tid < N_CLASSES_C)
        out[g * N_CLASSES_C + tid] = lg[tid] - lse;
}

// -------------------------------------------------------------------------
extern "C" void kernel_launch(void* const* d_in, const int* in_sizes, int n_in,
                              void* d_out, int out_size, void* d_ws, size_t ws_size,
                              hipStream_t stream)
{
    const float* x         = (const float*)d_in[0];
    const float* edge_attr = (const float*)d_in[1];
    const int*   ei        = (const int*)d_in[2];
    const int*   batch     = (const int*)d_in[3];
    const float* ee_w1     = (const float*)d_in[4];
    const float* ee_b1     = (const float*)d_in[5];
    const float* ee_w2     = (const float*)d_in[6];
    const float* ee_b2     = (const float*)d_in[7];
    const float* ee_bn_g   = (const float*)d_in[8];
    const float* ee_bn_b   = (const float*)d_in[9];
    const float* ee_bn_rm  = (const float*)d_in[10];
    const float* ee_bn_rv  = (const float*)d_in[11];
    const float* mlp_w1    = (const float*)d_in[12];
    const float* mlp_b1    = (const float*)d_in[13];
    const float* mlp_w2    = (const float*)d_in[14];
    const float* mlp_b2    = (const float*)d_in[15];
    const float* mlp_bn_g  = (const float*)d_in[16];
    const float* mlp_bn_b  = (const float*)d_in[17];
    const float* mlp_bn_rm = (const float*)d_in[18];
    const float* mlp_bn_rv = (const float*)d_in[19];
    const float* lin1_w    = (const float*)d_in[20];
    const float* lin1_b    = (const float*)d_in[21];
    const float* lin2_w    = (const float*)d_in[22];
    const float* lin2_b    = (const float*)d_in[23];
    float* out = (float*)d_out;

    const int* src = ei;
    const int* dst = ei + N_EDGES_C;

    // ---- workspace layout: fixed part first, emb buffer takes the rest ----
    char* wsp = (char*)d_ws;
    unsigned short* xh0 = (unsigned short*)wsp; wsp += (size_t)N_NODES_C * DIM_C * 2; // 12.8 MB
    unsigned short* xh1 = (unsigned short*)wsp; wsp += (size_t)N_NODES_C * DIM_C * 2; // 12.8 MB
    float* agg   = (float*)wsp;          wsp += (size_t)N_NODES_C * DIM_C * 4;        // 25.6 MB
    unsigned short* eaPermH = (unsigned short*)wsp;
                                         wsp += (size_t)N_EDGES_C * EDGE_DIM_C * 2;   // 16 MB
    int* srcPerm = (int*)wsp;            wsp += (size_t)N_EDGES_C * 4;                // 2 MB
    int* cnt     = (int*)wsp;            wsp += 200704;
    int* offsets = (int*)wsp;            wsp += 200704;
    int* cursor  = (int*)wsp;            wsp += 200704;
    int* incl    = (int*)wsp;            wsp += 200704;
    int* bsum    = (int*)wsp;            wsp += 4096;
    int* goff    = (int*)wsp;            wsp += 4096;
    float* pooled = (float*)wsp;         wsp += (size_t)N_GRAPHS_C * DIM_C * 4;
    short* W1T   = (short*)wsp;          wsp += (size_t)N_LAYERS_C * 128 * 16 * 2;
    short* W2T   = (short*)wsp;          wsp += (size_t)N_LAYERS_C * 128 * 128 * 2;
    short* MT1   = (short*)wsp;          wsp += (size_t)N_LAYERS_C * 128 * 128 * 2;
    short* MT2   = (short*)wsp;          wsp += (size_t)N_LAYERS_C * 128 * 128 * 2;
    unsigned short* emb = (unsigned short*)wsp;   // rest of workspace

    // dynamic chunk: as many edge rows as fit (full 500k needs ~128 MB)
    size_t used = (size_t)(wsp - (char*)d_ws);
    size_t embRows = (ws_size > used) ? (ws_size - used) / ((size_t)DIM_C * 2) : 0;
    int chunk = (int)((embRows < (size_t)N_EDGES_C) ? embRows : (size_t)N_EDGES_C);
    if (chunk < 128) chunk = 128;

    // ---- preprocess ----
    wprep_kernel<<<12, 256, 0, stream>>>(ee_w1, ee_w2, mlp_w1, mlp_w2,
                                         W1T, W2T, MT1, MT2);
    xcvt_kernel<<<2048, 256, 0, stream>>>(x, xh0);
    hipMemsetAsync(cnt, 0, N_NODES_C * sizeof(int), stream);
    hist_kernel<<<(N_EDGES_C + 255) / 256, 256, 0, stream>>>(dst, cnt);
    scan1_kernel<<<SCAN_NB, 1024, 0, stream>>>(cnt, incl, bsum);
    scan2_kernel<<<1, 64, 0, stream>>>(bsum);
    scan3_kernel<<<SCAN_NB, 1024, 0, stream>>>(cnt, incl, bsum, offsets, cursor);
    scatter_kernel<<<(N_EDGES_C + 255) / 256, 256, 0, stream>>>(
        src, dst, edge_attr, cursor, srcPerm, eaPermH);
    goff_kernel<<<1, 512, 0, stream>>>(batch, goff);

    const unsigned short* xh_cur = xh0;
    unsigned short* xh_nxt = xh1;
    for (int i = 0; i < N_LAYERS_C; ++i) {
        for (int c0 = 0; c0 < N_EDGES_C; c0 += chunk) {
            int c1 = min(c0 + chunk, N_EDGES_C);
            emb_mfma<<<1024, 256, 0, stream>>>(
                eaPermH,
                W1T + (size_t)i * 128 * 16, ee_b1 + i * DIM_C,
                W2T + (size_t)i * 128 * 128, ee_b2 + i * DIM_C,
                ee_bn_g + i * DIM_C, ee_bn_b + i * DIM_C,
                ee_bn_rm + i * DIM_C, ee_bn_rv + i * DIM_C,
                emb, c0, c1 - c0);
            agg_kernel<<<(N_NODES_C + 7) / 8, 256, 0, stream>>>(
                emb, xh_cur, srcPerm, offsets, agg, c0, c1, c0 == 0 ? 1 : 0);
        }
        node_fused<<<782, 256, 0, stream>>>(
            xh_cur, agg,
            MT1 + (size_t)i * 128 * 128, mlp_b1 + i * DIM_C,
            MT2 + (size_t)i * 128 * 128, mlp_b2 + i * DIM_C,
            mlp_bn_g + i * DIM_C, mlp_bn_b + i * DIM_C,
            mlp_bn_rm + i * DIM_C, mlp_bn_rv + i * DIM_C,
            xh_nxt, N_NODES_C);
        const unsigned short* t = xh_cur;
        xh_cur = xh_nxt;
        xh_nxt = (unsigned short*)t;
        if (i == 0) xh_nxt = xh0;   // after layer 0: cur=xh1, next writes xh0
    }

    pool2_kernel<<<N_GRAPHS_C, 128, 0, stream>>>(xh_cur, goff, pooled);
    head_kernel<<<N_GRAPHS_C, 128, 0, stream>>>(pooled, lin1_w, lin1_b,
                                                lin2_w, lin2_b, out);
}

// Round 17
// 502.831 us; speedup vs baseline: 1.0598x; 1.0598x over previous
//
#include <hip/hip_runtime.h>

#define N_NODES_C 50000
#define N_EDGES_C 500000
#define EDGE_DIM_C 16
#define DIM_C 128
#define N_LAYERS_C 3
#define N_GRAPHS_C 512
#define N_CLASSES_C 10
#define BN_EPS_C 1e-5f

#define SCAN_NB ((N_NODES_C + 1023) / 1024)

typedef short bf16x8 __attribute__((ext_vector_type(8)));
typedef float f32x4  __attribute__((ext_vector_type(4)));

__device__ inline unsigned cvt_pk_bf16(float a, float b) {
    unsigned r;
    asm("v_cvt_pk_bf16_f32 %0, %1, %2" : "=v"(r) : "v"(a), "v"(b));
    return r;
}
__device__ inline float bf2f(unsigned short h) {
    union { unsigned u; float f; } v; v.u = ((unsigned)h) << 16;
    return v.f;
}
// non-temporal 8-byte load of 4 bf16 (emb row slice) — bypass L2 pollution
__device__ inline ushort4 nt_load_e4(const unsigned short* p) {
    const unsigned* q = (const unsigned*)p;
    unsigned a = __builtin_nontemporal_load(q);
    unsigned b = __builtin_nontemporal_load(q + 1);
    ushort4 r;
    r.x = (unsigned short)(a & 0xffff); r.y = (unsigned short)(a >> 16);
    r.z = (unsigned short)(b & 0xffff); r.w = (unsigned short)(b >> 16);
    return r;
}

// -------------------------------------------------------------------------
// Preprocessing: counting sort of edges by dst (once per launch)
// -------------------------------------------------------------------------
__global__ void hist_kernel(const int* __restrict__ dst, int* __restrict__ cnt)
{
    int e = blockIdx.x * blockDim.x + threadIdx.x;
    if (e < N_EDGES_C) atomicAdd(&cnt[dst[e]], 1);
}

__global__ __launch_bounds__(1024)
void scan1_kernel(const int* __restrict__ cnt, int* __restrict__ incl,
                  int* __restrict__ bsum)
{
    __shared__ int buf[1024];
    int i = blockIdx.x * 1024 + threadIdx.x;
    int v = (i < N_NODES_C) ? cnt[i] : 0;
    buf[threadIdx.x] = v;
    __syncthreads();
    for (int off = 1; off < 1024; off <<= 1) {
        int t = (threadIdx.x >= off) ? buf[threadIdx.x - off] : 0;
        __syncthreads();
        buf[threadIdx.x] += t;
        __syncthreads();
    }
    if (i < N_NODES_C) incl[i] = buf[threadIdx.x];
    if (threadIdx.x == 1023) bsum[blockIdx.x] = buf[1023];
}

__global__ void scan2_kernel(int* __restrict__ bsum)
{
    if (threadIdx.x == 0 && blockIdx.x == 0) {
        int run = 0;
        for (int b = 0; b < SCAN_NB; ++b) { int v = bsum[b]; bsum[b] = run; run += v; }
    }
}

__global__ __launch_bounds__(1024)
void scan3_kernel(const int* __restrict__ cnt, const int* __restrict__ incl,
                  const int* __restrict__ bsum,
                  int* __restrict__ offsets, int* __restrict__ cursor)
{
    int i = blockIdx.x * 1024 + threadIdx.x;
    if (i < N_NODES_C) {
        int inc = incl[i] + bsum[blockIdx.x];
        offsets[i + 1] = inc;
        cursor[i] = inc - cnt[i];
        if (i == 0) offsets[0] = 0;
    }
}

// permute edges by dst; edge_attr converted to bf16 (32 B/edge random write)
__global__ void scatter_kernel(const int* __restrict__ src,
                               const int* __restrict__ dst,
                               const float* __restrict__ ea,
                               int* __restrict__ cursor,
                               int* __restrict__ srcPerm,
                               unsigned short* __restrict__ eaPermH)
{
    int e = blockIdx.x * blockDim.x + threadIdx.x;
    if (e >= N_EDGES_C) return;
    int pos = atomicAdd(&cursor[dst[e]], 1);
    srcPerm[pos] = src[e];
    const float4* in = (const float4*)&ea[(size_t)e * EDGE_DIM_C];
    float4 a = in[0], b = in[1], c = in[2], d = in[3];
    uint4 lo, hi;
    lo.x = cvt_pk_bf16(a.x, a.y); lo.y = cvt_pk_bf16(a.z, a.w);
    lo.z = cvt_pk_bf16(b.x, b.y); lo.w = cvt_pk_bf16(b.z, b.w);
    hi.x = cvt_pk_bf16(c.x, c.y); hi.y = cvt_pk_bf16(c.z, c.w);
    hi.z = cvt_pk_bf16(d.x, d.y); hi.w = cvt_pk_bf16(d.z, d.w);
    uint4* outp = (uint4*)&eaPermH[(size_t)pos * EDGE_DIM_C];
    outp[0] = lo; outp[1] = hi;
}

// convert input node features f32 -> bf16 (once per launch)
__global__ __launch_bounds__(256)
void xcvt_kernel(const float* __restrict__ x, unsigned short* __restrict__ xh)
{
    const int total = N_NODES_C * DIM_C / 4;
    for (int i = blockIdx.x * blockDim.x + threadIdx.x; i < total;
         i += gridDim.x * blockDim.x) {
        float4 v = *(const float4*)&x[(size_t)i * 4];
        uint2 o;
        o.x = cvt_pk_bf16(v.x, v.y);
        o.y = cvt_pk_bf16(v.z, v.w);
        *(uint2*)&xh[(size_t)i * 4] = o;
    }
}

// graph boundaries: goff[g] = lower_bound(batch, g); batch is sorted
__global__ __launch_bounds__(512)
void goff_kernel(const int* __restrict__ batch, int* __restrict__ goff)
{
    int g = threadIdx.x;
    int lo = 0, hi = N_NODES_C;
    while (lo < hi) {
        int mid = (lo + hi) >> 1;
        if (batch[mid] < g) lo = mid + 1; else hi = mid;
    }
    goff[g] = lo;
    if (g == 0) goff[N_GRAPHS_C] = N_NODES_C;
}

// -------------------------------------------------------------------------
// Weight prep: transpose + bf16-convert all GEMM weights once per launch.
// -------------------------------------------------------------------------
__global__ __launch_bounds__(256)
void wprep_kernel(const float* __restrict__ ee_w1, const float* __restrict__ ee_w2,
                  const float* __restrict__ mlp_w1, const float* __restrict__ mlp_w2,
                  short* __restrict__ W1T, short* __restrict__ W2T,
                  short* __restrict__ MT1, short* __restrict__ MT2)
{
    int b = blockIdx.x;
    int l = b % 3;
    int which = b / 3;
    if (which == 0) {
        const float* in = ee_w1 + l * 16 * 128;
        short* outp = W1T + l * 128 * 16;
        for (int i = threadIdx.x; i < 2048; i += 256) {
            int f = i >> 4, k = i & 15;
            outp[i] = (short)(cvt_pk_bf16(in[k * 128 + f], 0.f) & 0xffff);
        }
    } else {
        const float* in = (which == 1 ? ee_w2 : which == 2 ? mlp_w1 : mlp_w2) + l * 128 * 128;
        short* outp = (which == 1 ? W2T : which == 2 ? MT1 : MT2) + l * 128 * 128;
        for (int i = threadIdx.x; i < 16384; i += 256) {
            int f = i >> 7, k = i & 127;
            outp[i] = (short)(cvt_pk_bf16(in[k * 128 + f], 0.f) & 0xffff);
        }
    }
}

// -------------------------------------------------------------------------
// MFMA edge-encoder: 64-edge tile, 4 waves x 32 cols (VGPR ~92).
// emb output staged in LDS then stored coalesced (regular stores: the L2
// lines act as producer->consumer prefetch for agg — NT store measured -6%).
// grid=1024 (measured opt).
// -------------------------------------------------------------------------
__global__ __launch_bounds__(256)
void emb_mfma(const unsigned short* __restrict__ eaPermH,
              const short* __restrict__ W1T, const float* __restrict__ b1,
              const short* __restrict__ W2T, const float* __restrict__ b2,
              const float* __restrict__ bng, const float* __restrict__ bnb,
              const float* __restrict__ bnrm, const float* __restrict__ bnrv,
              unsigned short* __restrict__ emb, int c0, int chunkN)
{
    __shared__ short t1s[64 * 128];   // 16 KB; t1, then e

    const int tid  = threadIdx.x;
    const int lane = tid & 63;
    const int w    = tid >> 6;       // col-group 0..3
    const int ln15 = lane & 15;
    const int g    = lane >> 4;
    const int colbase = w * 32;

    bf16x8 fw1[2], fw2[2][4];
    float b1v[2], b2v[2], scv[2], shv[2];
    #pragma unroll
    for (int ct = 0; ct < 2; ++ct) {
        int f = colbase + ct * 16 + ln15;
        if (g < 2) fw1[ct] = *(const bf16x8*)&W1T[f * 16 + g * 8];
        else       fw1[ct] = (bf16x8){0,0,0,0,0,0,0,0};
        #pragma unroll
        for (int kb = 0; kb < 4; ++kb)
            fw2[ct][kb] = *(const bf16x8*)&W2T[f * 128 + kb * 32 + g * 8];
        b1v[ct] = b1[f]; b2v[ct] = b2[f];
        float sc = bng[f] * rsqrtf(bnrv[f] + BN_EPS_C);
        scv[ct] = sc; shv[ct] = bnb[f] - bnrm[f] * sc;
    }

    const int niter = (chunkN + 63) / 64;
    for (int it = blockIdx.x; it < niter; it += gridDim.x) {
        const int eb = it * 64;

        // ---- stage1: t1 = relu(ea @ W1 + b1), K=16 zero-padded to 32 ----
        #pragma unroll
        for (int rt = 0; rt < 4; ++rt) {
            bf16x8 af;
            if (g < 2) {
                int erow = min(eb + rt * 16 + ln15, chunkN - 1);
                af = *(const bf16x8*)&eaPermH[(size_t)(c0 + erow) * EDGE_DIM_C + g * 8];
            } else {
                af = (bf16x8){0,0,0,0,0,0,0,0};
            }
            #pragma unroll
            for (int ct = 0; ct < 2; ++ct) {
                f32x4 a1 = { b1v[ct], b1v[ct], b1v[ct], b1v[ct] };
                a1 = __builtin_amdgcn_mfma_f32_16x16x32_bf16(af, fw1[ct], a1, 0, 0, 0);
                int col = colbase + ct * 16 + ln15;
                #pragma unroll
                for (int r = 0; r < 4; ++r) {
                    int row = rt * 16 + g * 4 + r;
                    int idx = (row * 128 + col) ^ ((row & 15) << 3);
                    t1s[idx] = (short)(cvt_pk_bf16(fmaxf(a1[r], 0.f), 0.f) & 0xffff);
                }
            }
        }
        __syncthreads();

        // ---- stage2: acc = t1 @ W2 + b2 ----
        f32x4 acc[4][2];
        #pragma unroll
        for (int rt = 0; rt < 4; ++rt)
            #pragma unroll
            for (int ct = 0; ct < 2; ++ct)
                acc[rt][ct] = (f32x4){ b2v[ct], b2v[ct], b2v[ct], b2v[ct] };

        #pragma unroll
        for (int rt = 0; rt < 4; ++rt) {
            bf16x8 a[4];
            int row = rt * 16 + ln15;
            #pragma unroll
            for (int kb = 0; kb < 4; ++kb) {
                int idx = (row * 128 + kb * 32 + g * 8) ^ ((row & 15) << 3);
                a[kb] = *(const bf16x8*)&t1s[idx];
            }
            #pragma unroll
            for (int ct = 0; ct < 2; ++ct)
                #pragma unroll
                for (int kb = 0; kb < 4; ++kb)
                    acc[rt][ct] = __builtin_amdgcn_mfma_f32_16x16x32_bf16(
                        a[kb], fw2[ct][kb], acc[rt][ct], 0, 0, 0);
        }
        __syncthreads();   // all reads of t1s done before overwrite

        // ---- epilogue: e = BN(relu(acc)) -> bf16 back into t1s ----
        #pragma unroll
        for (int rt = 0; rt < 4; ++rt)
            #pragma unroll
            for (int ct = 0; ct < 2; ++ct) {
                int col = colbase + ct * 16 + ln15;
                #pragma unroll
                for (int r = 0; r < 4; ++r) {
                    int row = rt * 16 + g * 4 + r;
                    float v = fmaxf(acc[rt][ct][r], 0.f) * scv[ct] + shv[ct];
                    int idx = (row * 128 + col) ^ ((row & 15) << 3);
                    t1s[idx] = (short)(cvt_pk_bf16(v, 0.f) & 0xffff);
                }
            }
        __syncthreads();

        // ---- coalesced store: 64 rows x 128 cols bf16 = 1024 short8 ----
        for (int i = tid; i < 1024; i += 256) {
            int row = i >> 4;
            int c8  = (i & 15) * 8;
            if (eb + row < chunkN) {
                int idx = (row * 128 + c8) ^ ((row & 15) << 3);
                bf16x8 v = *(const bf16x8*)&t1s[idx];
                *(bf16x8*)&emb[(size_t)(eb + row) * 128 + c8] = v;
            }
        }
        __syncthreads();
    }
}

// -------------------------------------------------------------------------
// CSR aggregation (atomic-free): 32 lanes per node, 8 nodes per block.
// x gathered as bf16 rows; emb stream non-temporal. f32 agg across chunks.
// -------------------------------------------------------------------------
__global__ __launch_bounds__(256)
void agg_kernel(const unsigned short* __restrict__ emb,
                const unsigned short* __restrict__ xh,
                const int* __restrict__ srcPerm,
                const int* __restrict__ offsets,
                float* __restrict__ agg,
                int c0, int c1, int first)
{
    const int slot = threadIdx.x >> 5;
    const int l    = threadIdx.x & 31;
    const int n = blockIdx.x * 8 + slot;
    if (n >= N_NODES_C) return;

    int lo = offsets[n], hi = offsets[n + 1];
    lo = max(lo, c0); hi = min(hi, c1);

    float4 s = make_float4(0.f, 0.f, 0.f, 0.f);
    const bool any = lo < hi;
    for (int pos = lo; pos < hi; ++pos) {
        int srcn = srcPerm[pos];
        ushort4 eb = nt_load_e4(&emb[(size_t)(pos - c0) * DIM_C + l * 4]);
        ushort4 xv = *(const ushort4*)&xh[(size_t)srcn * DIM_C + l * 4];
        s.x += fmaxf(bf2f(xv.x) + bf2f(eb.x), 0.f);
        s.y += fmaxf(bf2f(xv.y) + bf2f(eb.y), 0.f);
        s.z += fmaxf(bf2f(xv.z) + bf2f(eb.z), 0.f);
        s.w += fmaxf(bf2f(xv.w) + bf2f(eb.w), 0.f);
    }

    float4* ap = (float4*)&agg[(size_t)n * DIM_C + l * 4];
    if (first) {
        *ap = s;
    } else if (any) {
        float4 o = *ap;
        o.x += s.x; o.y += s.y; o.z += s.z; o.w += s.w;
        *ap = o;
    }
}

// -------------------------------------------------------------------------
// Fused node MLP: xh' = bf16(BN(relu(relu((xh+agg)@W1+b1)@W2+b2))).
// Reads bf16 xh + f32 agg; writes bf16 xh_next (coalesced via LDS).
// -------------------------------------------------------------------------
__global__ __launch_bounds__(256)
void node_fused(const unsigned short* __restrict__ xh,
                const float* __restrict__ agg,
                const short* __restrict__ WT1, const float* __restrict__ b1,
                const short* __restrict__ WT2, const float* __restrict__ b2,
                const float* __restrict__ bng, const float* __restrict__ bnb,
                const float* __restrict__ bnrm, const float* __restrict__ bnrv,
                unsigned short* __restrict__ xhOut, int nrows)
{
    __shared__ short smem[2 * 64 * 128];   // 32 KB: hs | t1s; t1s reused as out
    short* hs  = smem;
    short* t1s = smem + 64 * 128;
    short* souts = t1s;                    // bf16 out overlay (t1s dead then)

    const int tid  = threadIdx.x;
    const int lane = tid & 63;
    const int w    = tid >> 6;
    const int ln15 = lane & 15;
    const int g    = lane >> 4;
    const int colbase = w * 32;

    bf16x8 fw1[2][4], fw2[2][4];
    float b1v[2], b2v[2], scv[2], shv[2];
    #pragma unroll
    for (int ct = 0; ct < 2; ++ct) {
        int f = colbase + ct * 16 + ln15;
        #pragma unroll
        for (int kb = 0; kb < 4; ++kb) {
            fw1[ct][kb] = *(const bf16x8*)&WT1[f * 128 + kb * 32 + g * 8];
            fw2[ct][kb] = *(const bf16x8*)&WT2[f * 128 + kb * 32 + g * 8];
        }
        b1v[ct] = b1[f]; b2v[ct] = b2[f];
        float sc = bng[f] * rsqrtf(bnrv[f] + BN_EPS_C);
        scv[ct] = sc; shv[ct] = bnb[f] - bnrm[f] * sc;
    }

    const int ntiles = (nrows + 63) / 64;
    for (int t = blockIdx.x; t < ntiles; t += gridDim.x) {
        const int base = t * 64;

        // ---- stage0: (bf16 xh + f32 agg) -> bf16 swizzled hs ----
        for (int i = tid; i < 2048; i += 256) {
            int row = i >> 5;
            int c4  = (i & 31) * 4;
            int rr  = min(base + row, nrows - 1);
            ushort4 xv = *(const ushort4*)&xh[(size_t)rr * DIM_C + c4];
            float4 a1 = *(const float4*)&agg[(size_t)rr * DIM_C + c4];
            float vx = bf2f(xv.x) + a1.x;
            float vy = bf2f(xv.y) + a1.y;
            float vz = bf2f(xv.z) + a1.z;
            float vw = bf2f(xv.w) + a1.w;
            int idx = (row * 128 + c4) ^ ((row & 15) << 3);
            *(unsigned*)&hs[idx]     = cvt_pk_bf16(vx, vy);
            *(unsigned*)&hs[idx + 2] = cvt_pk_bf16(vz, vw);
        }
        __syncthreads();

        // ---- stage1: h1 = relu(hs @ W1 + b1) -> t1s ----
        #pragma unroll
        for (int rt = 0; rt < 4; ++rt) {
            bf16x8 a[4];
            int row = rt * 16 + ln15;
            #pragma unroll
            for (int kb = 0; kb < 4; ++kb) {
                int idx = (row * 128 + kb * 32 + g * 8) ^ ((row & 15) << 3);
                a[kb] = *(const bf16x8*)&hs[idx];
            }
            #pragma unroll
            for (int ct = 0; ct < 2; ++ct) {
                f32x4 a1 = { b1v[ct], b1v[ct], b1v[ct], b1v[ct] };
                #pragma unroll
                for (int kb = 0; kb < 4; ++kb)
                    a1 = __builtin_amdgcn_mfma_f32_16x16x32_bf16(a[kb], fw1[ct][kb], a1, 0, 0, 0);
                int col = colbase + ct * 16 + ln15;
                #pragma unroll
                for (int r = 0; r < 4; ++r) {
                    int orow = rt * 16 + g * 4 + r;
                    int idx = (orow * 128 + col) ^ ((orow & 15) << 3);
                    t1s[idx] = (short)(cvt_pk_bf16(fmaxf(a1[r], 0.f), 0.f) & 0xffff);
                }
            }
        }
        __syncthreads();

        // ---- stage2: acc = t1s @ W2 + b2 (keep in registers) ----
        f32x4 acc[4][2];
        #pragma unroll
        for (int rt = 0; rt < 4; ++rt)
            #pragma unroll
            for (int ct = 0; ct < 2; ++ct)
                acc[rt][ct] = (f32x4){ b2v[ct], b2v[ct], b2v[ct], b2v[ct] };

        #pragma unroll
        for (int rt = 0; rt < 4; ++rt) {
            bf16x8 a[4];
            int row = rt * 16 + ln15;
            #pragma unroll
            for (int kb = 0; kb < 4; ++kb) {
                int idx = (row * 128 + kb * 32 + g * 8) ^ ((row & 15) << 3);
                a[kb] = *(const bf16x8*)&t1s[idx];
            }
            #pragma unroll
            for (int ct = 0; ct < 2; ++ct)
                #pragma unroll
                for (int kb = 0; kb < 4; ++kb)
                    acc[rt][ct] = __builtin_amdgcn_mfma_f32_16x16x32_bf16(
                        a[kb], fw2[ct][kb], acc[rt][ct], 0, 0, 0);
        }
        __syncthreads();   // t1s now dead -> reuse as bf16 out

        // ---- epilogue: BN -> bf16 into souts (swizzled) ----
        #pragma unroll
        for (int rt = 0; rt < 4; ++rt)
            #pragma unroll
            for (int ct = 0; ct < 2; ++ct) {
                int col = colbase + ct * 16 + ln15;
                #pragma unroll
                for (int r = 0; r < 4; ++r) {
                    int row = rt * 16 + g * 4 + r;
                    float v = fmaxf(acc[rt][ct][r], 0.f) * scv[ct] + shv[ct];
                    int idx = (row * 128 + col) ^ ((row & 15) << 3);
                    souts[idx] = (short)(cvt_pk_bf16(v, 0.f) & 0xffff);
                }
            }
        __syncthreads();

        // ---- coalesced store: 64 rows x 16 short8 ----
        for (int i = tid; i < 1024; i += 256) {
            int row = i >> 4;
            int c8  = (i & 15) * 8;
            int orow = base + row;
            if (orow < nrows) {
                int idx = (row * 128 + c8) ^ ((row & 15) << 3);
                bf16x8 v = *(const bf16x8*)&souts[idx];
                *(bf16x8*)&xhOut[(size_t)orow * DIM_C + c8] = v;
            }
        }
        __syncthreads();
    }
}

// -------------------------------------------------------------------------
// Segmented mean pool (bf16 input): one block per graph, batch is sorted.
// -------------------------------------------------------------------------
__global__ __launch_bounds__(128)
void pool2_kernel(const unsigned short* __restrict__ xh,
                  const int* __restrict__ goff,
                  float* __restrict__ pooled)
{
    const int g = blockIdx.x;
    const int tid = threadIdx.x;
    int lo = goff[g], hi = goff[g + 1];
    float s = 0.f;
    for (int n = lo; n < hi; ++n)
        s += bf2f(xh[(size_t)n * DIM_C + tid]);
    float c = (float)max(hi - lo, 1);
    pooled[g * DIM_C + tid] = s / c;
}

// -------------------------------------------------------------------------
// Readout head
// -------------------------------------------------------------------------
__global__ __launch_bounds__(128)
void head_kernel(const float* __restrict__ pooled,
                 const float* __restrict__ l1w,
                 const float* __restrict__ l1b,
                 const float* __restrict__ l2w,
                 const float* __restrict__ l2b,
                 float* __restrict__ out)
{
    const int g = blockIdx.x;
    const int tid = threadIdx.x;
    __shared__ float ps[DIM_C];
    __shared__ float hsx[DIM_C];
    __shared__ float lg[N_CLASSES_C];
    __shared__ float lse;

    ps[tid] = pooled[g * DIM_C + tid];
    __syncthreads();

    float a = l1b[tid];
    for (int k = 0; k < DIM_C; ++k)
        a += ps[k] * l1w[k * DIM_C + tid];
    hsx[tid] = fmaxf(a, 0.f);
    __syncthreads();

    if (tid < N_CLASSES_C) {
        float s = l2b[tid];
        for (int f = 0; f < DIM_C; ++f)
            s += hsx[f] * l2w[f * N_CLASSES_C + tid];
        lg[tid] = s;
    }
    __syncthreads();

    if (tid == 0) {
        float m = lg[0];
        for (int cc = 1; cc < N_CLASSES_C; ++cc) m = fmaxf(m, lg[cc]);
        float s = 0.f;
        for (int cc = 0; cc < N_CLASSES_C; ++cc) s += expf(lg[cc] - m);
        lse = m + logf(s);
    }
    __syncthreads();

    if (tid < N_CLASSES_C)
        out[g * N_CLASSES_C + tid] = lg[tid] - lse;
}

// -------------------------------------------------------------------------
extern "C" void kernel_launch(void* const* d_in, const int* in_sizes, int n_in,
                              void* d_out, int out_size, void* d_ws, size_t ws_size,
                              hipStream_t stream)
{
    const float* x         = (const float*)d_in[0];
    const float* edge_attr = (const float*)d_in[1];
    const int*   ei        = (const int*)d_in[2];
    const int*   batch     = (const int*)d_in[3];
    const float* ee_w1     = (const float*)d_in[4];
    const float* ee_b1     = (const float*)d_in[5];
    const float* ee_w2     = (const float*)d_in[6];
    const float* ee_b2     = (const float*)d_in[7];
    const float* ee_bn_g   = (const float*)d_in[8];
    const float* ee_bn_b   = (const float*)d_in[9];
    const float* ee_bn_rm  = (const float*)d_in[10];
    const float* ee_bn_rv  = (const float*)d_in[11];
    const float* mlp_w1    = (const float*)d_in[12];
    const float* mlp_b1    = (const float*)d_in[13];
    const float* mlp_w2    = (const float*)d_in[14];
    const float* mlp_b2    = (const float*)d_in[15];
    const float* mlp_bn_g  = (const float*)d_in[16];
    const float* mlp_bn_b  = (const float*)d_in[17];
    const float* mlp_bn_rm = (const float*)d_in[18];
    const float* mlp_bn_rv = (const float*)d_in[19];
    const float* lin1_w    = (const float*)d_in[20];
    const float* lin1_b    = (const float*)d_in[21];
    const float* lin2_w    = (const float*)d_in[22];
    const float* lin2_b    = (const float*)d_in[23];
    float* out = (float*)d_out;

    const int* src = ei;
    const int* dst = ei + N_EDGES_C;

    // ---- workspace layout: fixed part first, emb buffer takes the rest ----
    char* wsp = (char*)d_ws;
    unsigned short* xh0 = (unsigned short*)wsp; wsp += (size_t)N_NODES_C * DIM_C * 2; // 12.8 MB
    unsigned short* xh1 = (unsigned short*)wsp; wsp += (size_t)N_NODES_C * DIM_C * 2; // 12.8 MB
    float* agg   = (float*)wsp;          wsp += (size_t)N_NODES_C * DIM_C * 4;        // 25.6 MB
    unsigned short* eaPermH = (unsigned short*)wsp;
                                         wsp += (size_t)N_EDGES_C * EDGE_DIM_C * 2;   // 16 MB
    int* srcPerm = (int*)wsp;            wsp += (size_t)N_EDGES_C * 4;                // 2 MB
    int* cnt     = (int*)wsp;            wsp += 200704;
    int* offsets = (int*)wsp;            wsp += 200704;
    int* cursor  = (int*)wsp;            wsp += 200704;
    int* incl    = (int*)wsp;            wsp += 200704;
    int* bsum    = (int*)wsp;            wsp += 4096;
    int* goff    = (int*)wsp;            wsp += 4096;
    float* pooled = (float*)wsp;         wsp += (size_t)N_GRAPHS_C * DIM_C * 4;
    short* W1T   = (short*)wsp;          wsp += (size_t)N_LAYERS_C * 128 * 16 * 2;
    short* W2T   = (short*)wsp;          wsp += (size_t)N_LAYERS_C * 128 * 128 * 2;
    short* MT1   = (short*)wsp;          wsp += (size_t)N_LAYERS_C * 128 * 128 * 2;
    short* MT2   = (short*)wsp;          wsp += (size_t)N_LAYERS_C * 128 * 128 * 2;
    unsigned short* emb = (unsigned short*)wsp;   // rest of workspace

    // dynamic chunk: as many edge rows as fit (full 500k needs ~128 MB)
    size_t used = (size_t)(wsp - (char*)d_ws);
    size_t embRows = (ws_size > used) ? (ws_size - used) / ((size_t)DIM_C * 2) : 0;
    int chunk = (int)((embRows < (size_t)N_EDGES_C) ? embRows : (size_t)N_EDGES_C);
    if (chunk < 128) chunk = 128;

    // ---- preprocess ----
    wprep_kernel<<<12, 256, 0, stream>>>(ee_w1, ee_w2, mlp_w1, mlp_w2,
                                         W1T, W2T, MT1, MT2);
    xcvt_kernel<<<2048, 256, 0, stream>>>(x, xh0);
    hipMemsetAsync(cnt, 0, N_NODES_C * sizeof(int), stream);
    hist_kernel<<<(N_EDGES_C + 255) / 256, 256, 0, stream>>>(dst, cnt);
    scan1_kernel<<<SCAN_NB, 1024, 0, stream>>>(cnt, incl, bsum);
    scan2_kernel<<<1, 64, 0, stream>>>(bsum);
    scan3_kernel<<<SCAN_NB, 1024, 0, stream>>>(cnt, incl, bsum, offsets, cursor);
    scatter_kernel<<<(N_EDGES_C + 255) / 256, 256, 0, stream>>>(
        src, dst, edge_attr, cursor, srcPerm, eaPermH);
    goff_kernel<<<1, 512, 0, stream>>>(batch, goff);

    const unsigned short* xh_cur = xh0;
    unsigned short* xh_nxt = xh1;
    for (int i = 0; i < N_LAYERS_C; ++i) {
        for (int c0 = 0; c0 < N_EDGES_C; c0 += chunk) {
            int c1 = min(c0 + chunk, N_EDGES_C);
            emb_mfma<<<1024, 256, 0, stream>>>(
                eaPermH,
                W1T + (size_t)i * 128 * 16, ee_b1 + i * DIM_C,
                W2T + (size_t)i * 128 * 128, ee_b2 + i * DIM_C,
                ee_bn_g + i * DIM_C, ee_bn_b + i * DIM_C,
                ee_bn_rm + i * DIM_C, ee_bn_rv + i * DIM_C,
                emb, c0, c1 - c0);
            agg_kernel<<<(N_NODES_C + 7) / 8, 256, 0, stream>>>(
                emb, xh_cur, srcPerm, offsets, agg, c0, c1, c0 == 0 ? 1 : 0);
        }
        node_fused<<<782, 256, 0, stream>>>(
            xh_cur, agg,
            MT1 + (size_t)i * 128 * 128, mlp_b1 + i * DIM_C,
            MT2 + (size_t)i * 128 * 128, mlp_b2 + i * DIM_C,
            mlp_bn_g + i * DIM_C, mlp_bn_b + i * DIM_C,
            mlp_bn_rm + i * DIM_C, mlp_bn_rv + i * DIM_C,
            xh_nxt, N_NODES_C);
        const unsigned short* t = xh_cur;
        xh_cur = xh_nxt;
        xh_nxt = (unsigned short*)t;
        if (i == 0) xh_nxt = xh0;   // after layer 0: cur=xh1, next writes xh0
    }

    pool2_kernel<<<N_GRAPHS_C, 128, 0, stream>>>(xh_cur, goff, pooled);
    head_kernel<<<N_GRAPHS_C, 128, 0, stream>>>(pooled, lin1_w, lin1_b,
                                                lin2_w, lin2_b, out);
}